// Round 3
// baseline (15835.649 us; speedup 1.0000x reference)
//
#include <hip/hip_runtime.h>
#include <math.h>

#define H   256
#define TT  128
#define BT  8
#define NTC 3
#define EE  8
#define PP  6

typedef float v2f __attribute__((ext_vector_type(2)));

__device__ __forceinline__ float sigf(float x) { return 1.0f / (1.0f + __expf(-x)); }
__device__ __forceinline__ float tanh_fast(float x) {
    float t = __expf(-2.0f * fabsf(x));
    float r = (1.0f - t) / (1.0f + t);
    return copysignf(r, x);
}

// ---------------- pack weights --------------------------------------------
// wbA [hf][k4'(32)][g(2: z,r)][t]      = {Uz0,Ur0}[t][4k4..], k4 = hf*32+k4'
// wbH [hf][k4'(32)][t]                 = Uh0[t][4k4..]
// wbC: C0  [k4 0..31][g(3: Wz,Wr,Wh)][t]   (h0n part, cols 0..127)
//      C0b [k4 32..63][g(2: Wz,Wr)][t]     (h0n part, cols 128..255)
//      C1  [k4 0..63][g(2: Uz,Ur)][t]      (h1 part)
//      C1b [k4 32..63][t]  (Wh1 cols 128..255)
// wbD [hf][k4'(32)][t]                 = Uh1[t][4k4..]
__global__ void pack_weights(const float* __restrict__ Uz0, const float* __restrict__ Ur0, const float* __restrict__ Uh0,
                             const float* __restrict__ Wz1, const float* __restrict__ Wr1, const float* __restrict__ Wh1,
                             const float* __restrict__ Uz1, const float* __restrict__ Ur1, const float* __restrict__ Uh1,
                             float4* __restrict__ wbA, float4* __restrict__ wbH,
                             float4* __restrict__ wbC, float4* __restrict__ wbD)
{
    int idx = blockIdx.x * 256 + threadIdx.x;   // 0..147455
    if (idx < 32768) {
        int hf = idx >> 14; int r = idx & 16383;
        int k4 = hf * 32 + (r >> 9); int g = (r >> 8) & 1; int t = r & 255;
        const float* p = (g ? Ur0 : Uz0) + t * H + k4 * 4;
        wbA[idx] = make_float4(p[0], p[1], p[2], p[3]);
    } else if (idx < 49152) {
        int i = idx - 32768;
        int hf = i >> 13; int r = i & 8191;
        int k4 = hf * 32 + (r >> 8); int t = r & 255;
        const float* p = Uh0 + t * H + k4 * 4;
        wbH[i] = make_float4(p[0], p[1], p[2], p[3]);
    } else if (idx < 131072) {
        int i = idx - 49152;  // 0..81919
        const float* p;
        if (i < 24576) {                 // C0
            int k4 = i / 768; int g = (i % 768) >> 8; int t = i & 255;
            const float* W = (g == 0) ? Wz1 : ((g == 1) ? Wr1 : Wh1);
            p = W + t * 264 + k4 * 4;
        } else if (i < 40960) {          // C0b
            int j = i - 24576;
            int k4 = 32 + (j >> 9); int g = (j >> 8) & 1; int t = j & 255;
            p = (g ? Wr1 : Wz1) + t * 264 + k4 * 4;
        } else if (i < 73728) {          // C1
            int j = i - 40960;
            int k4 = j >> 9; int g = (j >> 8) & 1; int t = j & 255;
            p = (g ? Ur1 : Uz1) + t * H + k4 * 4;
        } else {                         // C1b
            int j = i - 73728;
            int k4 = 32 + (j >> 8); int t = j & 255;
            p = Wh1 + t * 264 + k4 * 4;
        }
        wbC[i] = make_float4(p[0], p[1], p[2], p[3]);
    } else if (idx < 147456) {
        int i = idx - 131072;
        int hf = i >> 13; int r = i & 8191;
        int k4 = hf * 32 + (r >> 8); int t = r & 255;
        const float* p = Uh1 + t * H + k4 * 4;
        wbD[i] = make_float4(p[0], p[1], p[2], p[3]);
    }
}

// ---------------- per-class / per-unit constants (as r2) -------------------
__global__ void pack_consts(const float* __restrict__ Wz0, const float* __restrict__ Wr0, const float* __restrict__ Wh0,
                            const float* __restrict__ Vw0, const float* __restrict__ Vb0,
                            const float* __restrict__ lz0, const float* __restrict__ lr0, const float* __restrict__ lh0,
                            const float* __restrict__ Wz1, const float* __restrict__ Wr1, const float* __restrict__ Wh1,
                            const float* __restrict__ Vw1, const float* __restrict__ Vb1,
                            const float* __restrict__ lz1, const float* __restrict__ lr1, const float* __restrict__ lh1,
                            const float* __restrict__ emb, float* __restrict__ cst)
{
    int t = threadIdx.x;
    float* A0 = cst;         float* B1 = cst + 2304;
    float* I0 = cst + 4608;  float* I1 = cst + 5376;
    float* L0 = cst + 6144;  float* L1 = cst + 6912;
    float* WC = cst + 7680;
    const float* W0s[3] = {Wz0, Wr0, Wh0};
    const float* W1s[3] = {Wz1, Wr1, Wh1};
    const float* ls0[3] = {lz0, lr0, lh0};
    const float* ls1[3] = {lz1, lr1, lh1};
    for (int g = 0; g < 3; ++g) {
        WC[g * H + t] = W0s[g][t * 9];
        L0[g * H + t] = 0.05f + 0.45f * sigf(ls0[g][t]);
        L1[g * H + t] = 0.05f + 0.45f * sigf(ls1[g][t]);
        for (int c = 0; c < NTC; ++c) {
            float s0 = 0.f, s1 = 0.f;
            for (int e = 0; e < EE; ++e) {
                s0 += W0s[g][t * 9 + 1 + e]     * emb[c * EE + e];
                s1 += W1s[g][t * 264 + 256 + e] * emb[c * EE + e];
            }
            A0[(g * 3 + c) * H + t] = s0;
            B1[(g * 3 + c) * H + t] = s1;
        }
    }
    for (int c = 0; c < NTC; ++c) {
        float s0 = Vb0[t], s1 = Vb1[t];
        for (int e = 0; e < EE; ++e) {
            s0 += Vw0[t * EE + e] * emb[c * EE + e];
            s1 += Vw1[t * EE + e] * emb[c * EE + e];
        }
        I0[c * H + t] = s0;
        I1[c * H + t] = s1;
    }
}

// ---------------- persistent scan: 512 thr, K-split halves, BT=8 ----------
__global__ __launch_bounds__(512, 2) void trs_scan(
    const float* __restrict__ x,
    const float4* __restrict__ wbA, const float4* __restrict__ wbH,
    const float4* __restrict__ wbC, const float4* __restrict__ wbD,
    const float* __restrict__ cst, const float* __restrict__ fcw, const float* __restrict__ fcb,
    float* __restrict__ out)
{
    __shared__ __align__(16) float h0s[BT][H];
    __shared__ __align__(16) float h1s[BT][H];
    __shared__ __align__(16) float rh0[BT][H];
    __shared__ __align__(16) float rh1[BT][H];
    __shared__ float pb0[BT][H], pb1[BT][H], pb2[BT][H];
    __shared__ float xm[BT][TT];
    __shared__ unsigned char xcl[BT][TT];

    const int tid = threadIdx.x;
    const int t  = tid & 255;
    const int hf = tid >> 8;
    const int r0 = blockIdx.x * BT;

    // per-thread constants for hidden unit t
    const float* A0 = cst;         const float* B1 = cst + 2304;
    const float* I0 = cst + 4608;  const float* I1 = cst + 5376;
    const float* L0 = cst + 6144;  const float* L1 = cst + 6912;
    const float* WC = cst + 7680;
    float az[3][3], b1c[3][3], i0v[3], i1v[3], l0[3], l1[3], wc[3];
    #pragma unroll
    for (int g = 0; g < 3; ++g) {
        wc[g] = WC[g * H + t]; l0[g] = L0[g * H + t]; l1[g] = L1[g * H + t];
        #pragma unroll
        for (int c = 0; c < 3; ++c) {
            az[g][c]  = A0[(g * 3 + c) * H + t];
            b1c[g][c] = B1[(g * 3 + c) * H + t];
        }
    }
    #pragma unroll
    for (int c = 0; c < 3; ++c) { i0v[c] = I0[c * H + t]; i1v[c] = I1[c * H + t]; }

    for (int i = tid; i < BT * TT; i += 512) {
        int b = i >> 7, tt = i & 127;
        float2 v = *(const float2*)(x + ((size_t)(r0 + b) * TT + tt) * 2);
        xm[b][tt] = v.x;
        int c = (int)v.y; c = c < 0 ? 0 : (c > 2 ? 2 : c);
        xcl[b][tt] = (unsigned char)c;
    }
    if (tid < 256) {
        #pragma unroll
        for (int b = 0; b < BT; ++b) { h0s[b][tid] = 0.f; h1s[b][tid] = 0.f; }
    }
    __syncthreads();

    const v2f vzero = {0.f, 0.f};

    for (int step = 0; step < TT; ++step) {
        float zv[BT], h0val[BT], mm[BT];
        float z1v[BT], h1val[BT], ahWv[BT];
        int cc[BT];

        // ===== Phase A: gates z,r; K-split (this half: k in [hf*128, +128)) =====
        v2f az2[BT], ar2[BT];
        #pragma unroll
        for (int b = 0; b < BT; ++b) { az2[b] = vzero; ar2[b] = vzero; }
        {
            const float4* pA = wbA + (hf << 14) + t;    // stride 512 per k4
            float4 wz[4], wr[4];
            #pragma unroll
            for (int i = 0; i < 3; ++i) { wz[i] = pA[i * 512]; wr[i] = pA[i * 512 + 256]; }
            const float* hbase = &h0s[0][hf << 7];
            for (int kb = 0; kb < 8; ++kb) {
                #pragma unroll
                for (int j = 0; j < 4; ++j) {
                    int k4 = kb * 4 + j;
                    int sl = (j + 3) & 3;
                    wz[sl] = pA[(k4 + 3) * 512];
                    wr[sl] = pA[(k4 + 3) * 512 + 256];
                    const float* hp = hbase + k4 * 4;
                    float4 W1 = wz[j], W2 = wr[j];
                    v2f w1l = {W1.x, W1.y}, w1h = {W1.z, W1.w};
                    v2f w2l = {W2.x, W2.y}, w2h = {W2.z, W2.w};
                    #pragma unroll
                    for (int b = 0; b < BT; ++b) {
                        float4 a = *(const float4*)(hp + (b << 8));
                        v2f alo = {a.x, a.y}, ahi = {a.z, a.w};
                        az2[b] += alo * w1l + ahi * w1h;
                        ar2[b] += alo * w2l + ahi * w2h;
                    }
                }
            }
        }
        if (hf) {
            #pragma unroll
            for (int b = 0; b < BT; ++b) { pb0[b][t] = az2[b][0] + az2[b][1]; pb1[b][t] = ar2[b][0] + ar2[b][1]; }
        }
        __syncthreads();
        if (!hf) {
            #pragma unroll
            for (int b = 0; b < BT; ++b) {
                cc[b] = xcl[b][step]; mm[b] = xm[b][step];
                int c = cc[b]; float m = mm[b];
                float gz = az2[b][0] + az2[b][1] + pb0[b][t];
                float gr = ar2[b][0] + ar2[b][1] + pb1[b][t];
                float z = sigf(gz + m * wc[0] + az[0][c] + l0[0] * i0v[c]);
                float r = sigf(gr + m * wc[1] + az[1][c] + l0[1] * i0v[c]);
                h0val[b] = h0s[b][t];
                zv[b] = z;
                rh0[b][t] = r * h0val[b];
            }
        }
        __syncthreads();

        // ===== Phase B: (r∘h0)·Uh0, K-split =====
        v2f ah2[BT];
        #pragma unroll
        for (int b = 0; b < BT; ++b) ah2[b] = vzero;
        {
            const float4* pB = wbH + (hf << 13) + t;    // stride 256
            float4 wh[4];
            #pragma unroll
            for (int i = 0; i < 3; ++i) wh[i] = pB[i * 256];
            const float* rbase = &rh0[0][hf << 7];
            for (int kb = 0; kb < 8; ++kb) {
                #pragma unroll
                for (int j = 0; j < 4; ++j) {
                    int k4 = kb * 4 + j;
                    wh[(j + 3) & 3] = pB[(k4 + 3) * 256];
                    const float* hp = rbase + k4 * 4;
                    float4 W1 = wh[j];
                    v2f w1l = {W1.x, W1.y}, w1h = {W1.z, W1.w};
                    #pragma unroll
                    for (int b = 0; b < BT; ++b) {
                        float4 a = *(const float4*)(hp + (b << 8));
                        v2f alo = {a.x, a.y}, ahi = {a.z, a.w};
                        ah2[b] += alo * w1l + ahi * w1h;
                    }
                }
            }
        }
        if (hf) {
            #pragma unroll
            for (int b = 0; b < BT; ++b) pb0[b][t] = ah2[b][0] + ah2[b][1];
        }
        __syncthreads();
        if (!hf) {
            #pragma unroll
            for (int b = 0; b < BT; ++b) {
                int c = cc[b];
                float acch = ah2[b][0] + ah2[b][1] + pb0[b][t];
                float ht = tanh_fast(mm[b] * wc[2] + az[2][c] + acch + l0[2] * i0v[c]);
                h0s[b][t] = (1.f - zv[b]) * h0val[b] + zv[b] * ht;
            }
        }
        __syncthreads();

        // ===== Phase C: z1,r1 (K=512 split h0/h1) + Wh1·h0n (k-split) =====
        v2f cz2[BT], cr2[BT], cw2[BT];
        #pragma unroll
        for (int b = 0; b < BT; ++b) { cz2[b] = vzero; cr2[b] = vzero; cw2[b] = vzero; }
        if (!hf) {
            // C0: k4 0..31, gates Wz,Wr,Wh over h0n
            const float4* p0 = wbC + t;                 // stride 768
            float4 qz[4], qr[4], qw[4];
            #pragma unroll
            for (int i = 0; i < 3; ++i) { qz[i] = p0[i * 768]; qr[i] = p0[i * 768 + 256]; qw[i] = p0[i * 768 + 512]; }
            for (int kb = 0; kb < 8; ++kb) {
                #pragma unroll
                for (int j = 0; j < 4; ++j) {
                    int k4 = kb * 4 + j;
                    int sl = (j + 3) & 3;
                    qz[sl] = p0[(k4 + 3) * 768];
                    qr[sl] = p0[(k4 + 3) * 768 + 256];
                    qw[sl] = p0[(k4 + 3) * 768 + 512];
                    const float* hp = &h0s[0][k4 * 4];
                    float4 W1 = qz[j], W2 = qr[j], W3 = qw[j];
                    v2f w1l = {W1.x, W1.y}, w1h = {W1.z, W1.w};
                    v2f w2l = {W2.x, W2.y}, w2h = {W2.z, W2.w};
                    v2f w3l = {W3.x, W3.y}, w3h = {W3.z, W3.w};
                    #pragma unroll
                    for (int b = 0; b < BT; ++b) {
                        float4 a = *(const float4*)(hp + (b << 8));
                        v2f alo = {a.x, a.y}, ahi = {a.z, a.w};
                        cz2[b] += alo * w1l + ahi * w1h;
                        cr2[b] += alo * w2l + ahi * w2h;
                        cw2[b] += alo * w3l + ahi * w3h;
                    }
                }
            }
            // C0b: k4 32..63, gates Wz,Wr over h0n
            const float4* p0b = wbC + 24576 + t;        // stride 512
            #pragma unroll
            for (int i = 0; i < 3; ++i) { qz[i] = p0b[i * 512]; qr[i] = p0b[i * 512 + 256]; }
            for (int kb = 0; kb < 8; ++kb) {
                #pragma unroll
                for (int j = 0; j < 4; ++j) {
                    int k4 = kb * 4 + j;
                    int sl = (j + 3) & 3;
                    qz[sl] = p0b[(k4 + 3) * 512];
                    qr[sl] = p0b[(k4 + 3) * 512 + 256];
                    const float* hp = &h0s[0][128 + k4 * 4];
                    float4 W1 = qz[j], W2 = qr[j];
                    v2f w1l = {W1.x, W1.y}, w1h = {W1.z, W1.w};
                    v2f w2l = {W2.x, W2.y}, w2h = {W2.z, W2.w};
                    #pragma unroll
                    for (int b = 0; b < BT; ++b) {
                        float4 a = *(const float4*)(hp + (b << 8));
                        v2f alo = {a.x, a.y}, ahi = {a.z, a.w};
                        cz2[b] += alo * w1l + ahi * w1h;
                        cr2[b] += alo * w2l + ahi * w2h;
                    }
                }
            }
        } else {
            // C1: k4 0..63, gates Uz,Ur over h1
            const float4* p1 = wbC + 40960 + t;         // stride 512
            float4 qz[4], qr[4], qw[4];
            #pragma unroll
            for (int i = 0; i < 3; ++i) { qz[i] = p1[i * 512]; qr[i] = p1[i * 512 + 256]; }
            for (int kb = 0; kb < 16; ++kb) {
                #pragma unroll
                for (int j = 0; j < 4; ++j) {
                    int k4 = kb * 4 + j;
                    int sl = (j + 3) & 3;
                    qz[sl] = p1[(k4 + 3) * 512];
                    qr[sl] = p1[(k4 + 3) * 512 + 256];
                    const float* hp = &h1s[0][k4 * 4];
                    float4 W1 = qz[j], W2 = qr[j];
                    v2f w1l = {W1.x, W1.y}, w1h = {W1.z, W1.w};
                    v2f w2l = {W2.x, W2.y}, w2h = {W2.z, W2.w};
                    #pragma unroll
                    for (int b = 0; b < BT; ++b) {
                        float4 a = *(const float4*)(hp + (b << 8));
                        v2f alo = {a.x, a.y}, ahi = {a.z, a.w};
                        cz2[b] += alo * w1l + ahi * w1h;
                        cr2[b] += alo * w2l + ahi * w2h;
                    }
                }
            }
            // C1b: k4 32..63, gate Wh over h0n (upper half)
            const float4* p1b = wbC + 73728 + t;        // stride 256
            #pragma unroll
            for (int i = 0; i < 3; ++i) qw[i] = p1b[i * 256];
            for (int kb = 0; kb < 8; ++kb) {
                #pragma unroll
                for (int j = 0; j < 4; ++j) {
                    int k4 = kb * 4 + j;
                    qw[(j + 3) & 3] = p1b[(k4 + 3) * 256];
                    const float* hp = &h0s[0][128 + k4 * 4];
                    float4 W3 = qw[j];
                    v2f w3l = {W3.x, W3.y}, w3h = {W3.z, W3.w};
                    #pragma unroll
                    for (int b = 0; b < BT; ++b) {
                        float4 a = *(const float4*)(hp + (b << 8));
                        v2f alo = {a.x, a.y}, ahi = {a.z, a.w};
                        cw2[b] += alo * w3l + ahi * w3h;
                    }
                }
            }
        }
        if (hf) {
            #pragma unroll
            for (int b = 0; b < BT; ++b) {
                pb0[b][t] = cz2[b][0] + cz2[b][1];
                pb1[b][t] = cr2[b][0] + cr2[b][1];
                pb2[b][t] = cw2[b][0] + cw2[b][1];
            }
        }
        __syncthreads();
        if (!hf) {
            #pragma unroll
            for (int b = 0; b < BT; ++b) {
                int c = cc[b];
                float g1z = cz2[b][0] + cz2[b][1] + pb0[b][t];
                float g1r = cr2[b][0] + cr2[b][1] + pb1[b][t];
                ahWv[b]  = cw2[b][0] + cw2[b][1] + pb2[b][t];
                float z1 = sigf(g1z + b1c[0][c] + l1[0] * i1v[c]);
                float r1 = sigf(g1r + b1c[1][c] + l1[1] * i1v[c]);
                h1val[b] = h1s[b][t];
                z1v[b] = z1;
                rh1[b][t] = r1 * h1val[b];
            }
        }
        __syncthreads();

        // ===== Phase D: (r1∘h1)·Uh1, K-split =====
        #pragma unroll
        for (int b = 0; b < BT; ++b) ah2[b] = vzero;
        {
            const float4* pD = wbD + (hf << 13) + t;    // stride 256
            float4 wh[4];
            #pragma unroll
            for (int i = 0; i < 3; ++i) wh[i] = pD[i * 256];
            const float* rbase = &rh1[0][hf << 7];
            for (int kb = 0; kb < 8; ++kb) {
                #pragma unroll
                for (int j = 0; j < 4; ++j) {
                    int k4 = kb * 4 + j;
                    wh[(j + 3) & 3] = pD[(k4 + 3) * 256];
                    const float* hp = rbase + k4 * 4;
                    float4 W1 = wh[j];
                    v2f w1l = {W1.x, W1.y}, w1h = {W1.z, W1.w};
                    #pragma unroll
                    for (int b = 0; b < BT; ++b) {
                        float4 a = *(const float4*)(hp + (b << 8));
                        v2f alo = {a.x, a.y}, ahi = {a.z, a.w};
                        ah2[b] += alo * w1l + ahi * w1h;
                    }
                }
            }
        }
        if (hf) {
            #pragma unroll
            for (int b = 0; b < BT; ++b) pb0[b][t] = ah2[b][0] + ah2[b][1];
        }
        __syncthreads();
        if (!hf) {
            #pragma unroll
            for (int b = 0; b < BT; ++b) {
                int c = cc[b];
                float ahU = ah2[b][0] + ah2[b][1] + pb0[b][t];
                float ht1 = tanh_fast(ahWv[b] + b1c[2][c] + ahU + l1[2] * i1v[c]);
                h1s[b][t] = (1.f - z1v[b]) * h1val[b] + z1v[b] * ht1;
            }
        }
        __syncthreads();
    }

    // ---- epilogue: out = h1 @ fc_w^T + fc_b
    if (tid < BT * PP) {
        int b = tid / PP, p = tid - b * PP;
        float s = fcb[p];
        for (int h = 0; h < H; ++h) s += h1s[b][h] * fcw[p * H + h];
        out[(size_t)(r0 + b) * PP + p] = s;
    }
}

extern "C" void kernel_launch(void* const* d_in, const int* in_sizes, int n_in,
                              void* d_out, int out_size, void* d_ws, size_t ws_size,
                              hipStream_t stream)
{
    const float* x   = (const float*)d_in[0];
    const float* emb = (const float*)d_in[1];
    const float* Wz0 = (const float*)d_in[2];  const float* Wr0 = (const float*)d_in[3];
    const float* Wh0 = (const float*)d_in[4];
    const float* Uz0 = (const float*)d_in[5];  const float* Ur0 = (const float*)d_in[6];
    const float* Uh0 = (const float*)d_in[7];
    const float* Vw0 = (const float*)d_in[8];  const float* Vb0 = (const float*)d_in[9];
    const float* lz0 = (const float*)d_in[10]; const float* lr0 = (const float*)d_in[11];
    const float* lh0 = (const float*)d_in[12];
    const float* Wz1 = (const float*)d_in[13]; const float* Wr1 = (const float*)d_in[14];
    const float* Wh1 = (const float*)d_in[15];
    const float* Uz1 = (const float*)d_in[16]; const float* Ur1 = (const float*)d_in[17];
    const float* Uh1 = (const float*)d_in[18];
    const float* Vw1 = (const float*)d_in[19]; const float* Vb1 = (const float*)d_in[20];
    const float* lz1 = (const float*)d_in[21]; const float* lr1 = (const float*)d_in[22];
    const float* lh1 = (const float*)d_in[23];
    const float* fcw = (const float*)d_in[24]; const float* fcb = (const float*)d_in[25];

    float*  ws  = (float*)d_ws;
    float4* wbA = (float4*)ws;                         // f4 [0, 32768)
    float4* wbH = (float4*)(ws + 131072);              // f4 [32768, 49152)
    float4* wbC = (float4*)(ws + 196608);              // f4 [49152, 131072)
    float4* wbD = (float4*)(ws + 524288);              // f4 [131072, 147456)
    float*  cst = ws + 589824;                         // 8448 floats (also absorbs prefetch over-reads)

    hipLaunchKernelGGL(pack_weights, dim3(576), dim3(256), 0, stream,
                       Uz0, Ur0, Uh0, Wz1, Wr1, Wh1, Uz1, Ur1, Uh1, wbA, wbH, wbC, wbD);
    hipLaunchKernelGGL(pack_consts, dim3(1), dim3(256), 0, stream,
                       Wz0, Wr0, Wh0, Vw0, Vb0, lz0, lr0, lh0,
                       Wz1, Wr1, Wh1, Vw1, Vb1, lz1, lr1, lh1, emb, cst);
    hipLaunchKernelGGL(trs_scan, dim3(2048 / BT), dim3(512), 0, stream,
                       x, wbA, wbH, wbC, wbD, cst, fcw, fcb, (float*)d_out);
}